// Round 5
// baseline (1814.887 us; speedup 1.0000x reference)
//
#include <hip/hip_runtime.h>
#include <hip/hip_fp16.h>
#include <stdint.h>

#define D 256
#define CHSH 13   // column-chunk shift: 8192 nodes/chunk = 4.2 MB bf16 rows ~ per-XCD L2
#define NPW 25    // nodes per wave in k_spmm (register accumulators, statically indexed)

typedef __attribute__((ext_vector_type(8))) short short8;
typedef __attribute__((ext_vector_type(4))) float floatx4;

__device__ __forceinline__ ushort f2bf(float f) {
    union { float f; uint32_t u; } v; v.f = f;
    uint32_t u = v.u;
    u += 0x7fffu + ((u >> 16) & 1u);   // RNE
    return (ushort)(u >> 16);
}
__device__ __forceinline__ float bf2f(ushort h) {
    union { uint32_t u; float f; } v; v.u = ((uint32_t)h) << 16;
    return v.f;
}

// padded bucket size: ceil4(count), and empty buckets still get ONE group of 4
// zero-pad slots so the spmm phase-1 body is branchless per bucket.
__device__ __forceinline__ int pad4(int x) {
    return ((x + 3) & ~3) + ((x == 0) ? 4 : 0);
}

// ---------------- bucketed CSR build ----------------
// CHUNK-MAJOR bucket id = (col>>CHSH)*n + row. Within a chunk, a wave's NPW
// node buckets are contiguous in bucket space AND in csr, so the wave's
// boundary loads per chunk are one contiguous scalar run and the wave's whole
// per-chunk edge range is contiguous.
// Buckets padded to min-4 / multiple-of-4; pad slots hold payload 0
// (col 0, val +0.0 -> gather of always-hot row 0 scaled by 0).

// hist + aux-record build: aux[e] = bucket<<32 | (col<<15 | half(val))
// aux is aliased onto X1 (dead until spmm).
__global__ void k_hist(const int* __restrict__ er, const int* __restrict__ ec,
                       const float* __restrict__ ev,
                       int* __restrict__ bp, uint64_t* __restrict__ aux,
                       int E, int n) {
    int e = blockIdx.x * 256 + threadIdx.x;
    if (e >= E) return;
    int row = er[e];
    int col = ec[e];
    int b = (col >> CHSH) * n + row;
    atomicAdd(&bp[b], 1);
    ushort hb = __half_as_ushort(__float2half_rn(ev[e]));   // val in [0,1/32): sign bit free
    uint32_t payload = ((uint32_t)col << 15) | (uint32_t)hb;
    aux[e] = ((uint64_t)(uint32_t)b << 32) | payload;
}

// block b sums PADDED counts pad4(bp[i]) over bp[b*1024 .. b*1024+1023] -> part[b]
__global__ void k_red(const int* __restrict__ bp, int* __restrict__ part, int nb) {
    __shared__ int s[256];
    int t = threadIdx.x;
    int base = blockIdx.x * 1024 + t * 4;
    int v = 0;
#pragma unroll
    for (int j = 0; j < 4; ++j) if (base + j < nb) v += pad4(bp[base + j]);
    s[t] = v; __syncthreads();
    for (int off = 128; off; off >>= 1) {
        if (t < off) s[t] += s[t + off];
        __syncthreads();
    }
    if (t == 0) part[blockIdx.x] = s[0];
}

// exclusive scan of part[0..np), np <= 2048, one block of 1024
__global__ __launch_bounds__(1024) void k_scanpart(int* __restrict__ part, int np) {
    __shared__ int s[1024];
    int t = threadIdx.x;
    int p0 = (2 * t < np) ? part[2 * t] : 0;
    int p1 = (2 * t + 1 < np) ? part[2 * t + 1] : 0;
    int v = p0 + p1;
    s[t] = v; __syncthreads();
    for (int off = 1; off < 1024; off <<= 1) {
        int x = (t >= off) ? s[t - off] : 0;
        __syncthreads();
        s[t] += x;
        __syncthreads();
    }
    int excl = s[t] - v;
    if (2 * t < np) part[2 * t] = excl;
    if (2 * t + 1 < np) part[2 * t + 1] = excl + p0;
}

// in-place exclusive scan of PADDED counts within each 1024 chunk, + part[b].
// Writes both bp (bumped by scatter) and pristine bp2 (+ sentinel bp2[nb]=total).
__global__ void k_scan3(int* __restrict__ bp, int* __restrict__ bp2,
                        const int* __restrict__ part, int nb) {
    __shared__ int s[256];
    int t = threadIdx.x;
    int base = blockIdx.x * 1024 + t * 4;
    int p0 = 0, p1 = 0, p2 = 0, p3 = 0;
    if (base     < nb) p0 = pad4(bp[base]);
    if (base + 1 < nb) p1 = pad4(bp[base + 1]);
    if (base + 2 < nb) p2 = pad4(bp[base + 2]);
    if (base + 3 < nb) p3 = pad4(bp[base + 3]);
    int sum = p0 + p1 + p2 + p3;
    s[t] = sum; __syncthreads();
    for (int off = 1; off < 256; off <<= 1) {
        int x = (t >= off) ? s[t - off] : 0;
        __syncthreads();
        s[t] += x;
        __syncthreads();
    }
    int run = part[blockIdx.x] + s[t] - sum;   // exclusive prefix (padded)
    if (base     < nb) { bp[base]     = run; bp2[base]     = run; if (base     == nb - 1) bp2[nb] = run + p0; } run += p0;
    if (base + 1 < nb) { bp[base + 1] = run; bp2[base + 1] = run; if (base + 1 == nb - 1) bp2[nb] = run + p1; } run += p1;
    if (base + 2 < nb) { bp[base + 2] = run; bp2[base + 2] = run; if (base + 2 == nb - 1) bp2[nb] = run + p2; } run += p2;
    if (base + 3 < nb) { bp[base + 3] = run; bp2[base + 3] = run; if (base + 3 == nb - 1) bp2[nb] = run + p3; }
}

// windowed, XCD-pinned scatter. 8 windows, window w = buckets [w*BW,(w+1)*BW),
// processed only by blocks with blockIdx&7 == w. Each window's csr slice and bp
// slice stay ~resident in one XCD's L2 so scattered 4B writes merge into full
// lines. aux re-scans absorbed by L3. Real edges fill the FRONT of each padded
// bucket; pad slots keep their pre-zeroed payload.
__global__ void k_scatter(const uint64_t* __restrict__ aux,
                          int* __restrict__ bp, uint32_t* __restrict__ csr,
                          int E, int BW) {
    int xcd = blockIdx.x & 7;            // = window id
    int j = blockIdx.x >> 3;
    int e = j * 256 + threadIdx.x;
    if (e >= E) return;
    uint64_t a = aux[e];
    int b = (int)(a >> 32);
    int lo = xcd * BW;
    if (b < lo || b >= lo + BW) return;  // not this window's edge
    int p = atomicAdd(&bp[b], 1);
    csr[p] = (uint32_t)a;
}

// ---------------- conversions (ego + W fused) ----------------
__global__ void k_cvt(const float4* __restrict__ ego, ushort4* __restrict__ ego_bf,
                      const float4* __restrict__ W1, const float4* __restrict__ W2,
                      ushort4* __restrict__ W1b, ushort4* __restrict__ W2b, int n4) {
    int i = blockIdx.x * 256 + threadIdx.x;
    const float4* src;
    ushort4* dst;
    if (i < n4) { src = ego + i; dst = ego_bf + i; }
    else {
        int j = i - n4;
        if (j >= 32768) return;
        int k = j & 16383;
        src = ((j < 16384) ? W1 : W2) + k;
        dst = ((j < 16384) ? W1b : W2b) + k;
    }
    float4 f = *src;
    ushort4 u;
    u.x = f2bf(f.x); u.y = f2bf(f.y); u.z = f2bf(f.z); u.w = f2bf(f.w);
    *dst = u;
}

// ---------------- SpMM + bi-interaction inputs ----------------
// Phase-coherent chunk-major sweep (R2 geometry: NPW=25, ~single generation),
// restructured for cross-bucket memory-level parallelism:
//   phase 1: the FIRST group of every one of the wave's NPW buckets --
//            guaranteed to exist by min-4 padding, statically unrolled,
//            branchless: 25 independent {scalar csr load -> 4 coalesced
//            row-gathers -> FMA} bodies in one basic block, free to pipeline.
//   phase 2: leftover groups (bucket len > 4, ~10% of buckets) in the old
//            dynamic per-bucket loops.
#define GROUP(ii, ee) do {                                                    \
    int e_ = (ee);                                                            \
    uint32_t w0 = csr[e_], w1 = csr[e_ + 1], w2 = csr[e_ + 2], w3 = csr[e_ + 3]; \
    ushort4 u0 = *(const ushort4*)(ego_bf + (size_t)(w0 >> 15) * D + d0);     \
    ushort4 u1 = *(const ushort4*)(ego_bf + (size_t)(w1 >> 15) * D + d0);     \
    ushort4 u2 = *(const ushort4*)(ego_bf + (size_t)(w2 >> 15) * D + d0);     \
    ushort4 u3 = *(const ushort4*)(ego_bf + (size_t)(w3 >> 15) * D + d0);     \
    float v0 = __half2float(__ushort_as_half((ushort)(w0 & 0x7fff)));         \
    float v1 = __half2float(__ushort_as_half((ushort)(w1 & 0x7fff)));         \
    float v2 = __half2float(__ushort_as_half((ushort)(w2 & 0x7fff)));         \
    float v3 = __half2float(__ushort_as_half((ushort)(w3 & 0x7fff)));         \
    acc[ii][0] += v0 * bf2f(u0.x); acc[ii][1] += v0 * bf2f(u0.y);             \
    acc[ii][2] += v0 * bf2f(u0.z); acc[ii][3] += v0 * bf2f(u0.w);             \
    acc[ii][0] += v1 * bf2f(u1.x); acc[ii][1] += v1 * bf2f(u1.y);             \
    acc[ii][2] += v1 * bf2f(u1.z); acc[ii][3] += v1 * bf2f(u1.w);             \
    acc[ii][0] += v2 * bf2f(u2.x); acc[ii][1] += v2 * bf2f(u2.y);             \
    acc[ii][2] += v2 * bf2f(u2.z); acc[ii][3] += v2 * bf2f(u2.w);             \
    acc[ii][0] += v3 * bf2f(u3.x); acc[ii][1] += v3 * bf2f(u3.y);             \
    acc[ii][2] += v3 * bf2f(u3.z); acc[ii][3] += v3 * bf2f(u3.w);             \
} while (0)

__global__ __launch_bounds__(256, 3) void k_spmm(
        const ushort* __restrict__ ego_bf, const int* __restrict__ bp2,
        const uint32_t* __restrict__ csr,
        ushort* __restrict__ X1, ushort* __restrict__ X2, int n, int NCH, int nb) {
    int wid = __builtin_amdgcn_readfirstlane(blockIdx.x * 4 + (threadIdx.x >> 6));
    int lane = threadIdx.x & 63;
    int node0 = wid * NPW;
    if (node0 >= n) return;
    int d0 = lane * 4;

    float acc[NPW][4];
#pragma unroll
    for (int i = 0; i < NPW; ++i) {
        acc[i][0] = 0.f; acc[i][1] = 0.f; acc[i][2] = 0.f; acc[i][3] = 0.f;
    }

    bool full = (node0 + NPW <= n);   // wave-uniform
    for (int c = 0; c < NCH; ++c) {
        int B[NPW + 1];
#pragma unroll
        for (int i = 0; i <= NPW; ++i) {
            int idx = c * n + node0 + i;          // wave-uniform -> scalar loads
            B[i] = bp2[idx > nb ? nb : idx];      // padded exclusive starts
        }
        if (full) {
            // phase 1: branchless first group of each bucket (min-4 padding)
#pragma unroll
            for (int i = 0; i < NPW; ++i) GROUP(i, B[i]);
            // phase 2: rare leftover groups
#pragma unroll
            for (int i = 0; i < NPW; ++i)
                for (int e = B[i] + 4; e < B[i + 1]; e += 4) GROUP(i, e);
        } else {
            // boundary wave fallback (never taken for n % NPW == 0)
#pragma unroll
            for (int i = 0; i < NPW; ++i)
                if (node0 + i < n)
                    for (int e = B[i]; e < B[i + 1]; e += 4) GROUP(i, e);
        }
    }

#pragma unroll
    for (int i = 0; i < NPW; ++i) {
        int node = node0 + i;
        if (node < n) {
            ushort4 eg = *(const ushort4*)(ego_bf + (size_t)node * D + d0);
            float e0 = bf2f(eg.x), e1 = bf2f(eg.y), e2 = bf2f(eg.z), e3 = bf2f(eg.w);
            ushort4 o1, o2;
            o1.x = f2bf(e0 + acc[i][0]); o2.x = f2bf(e0 * acc[i][0]);
            o1.y = f2bf(e1 + acc[i][1]); o2.y = f2bf(e1 * acc[i][1]);
            o1.z = f2bf(e2 + acc[i][2]); o2.z = f2bf(e2 * acc[i][2]);
            o1.w = f2bf(e3 + acc[i][3]); o2.w = f2bf(e3 * acc[i][3]);
            *(ushort4*)(X1 + (size_t)node * D + d0) = o1;
            *(ushort4*)(X2 + (size_t)node * D + d0) = o2;
        }
    }
}

// ---------------- fused dual GEMM + epilogue ----------------
__global__ __launch_bounds__(256) void k_gemm(
        const ushort* __restrict__ X1, const ushort* __restrict__ X2,
        const ushort* __restrict__ W1b, const ushort* __restrict__ W2b,
        const float* __restrict__ b1, const float* __restrict__ b2,
        float* __restrict__ out, int n) {
    int lane = threadIdx.x & 63;
    int w = threadIdx.x >> 6;
    int l16 = lane & 15, quad = lane >> 4;
    int row0 = blockIdx.x * 64;
    int colw = w * 64;

    floatx4 acc1[4][4], acc2[4][4];
#pragma unroll
    for (int i = 0; i < 4; ++i)
#pragma unroll
        for (int j = 0; j < 4; ++j) { acc1[i][j] = (floatx4)0.f; acc2[i][j] = (floatx4)0.f; }

    for (int kk = 0; kk < D; kk += 32) {
        short8 a[4], b[4];
#pragma unroll
        for (int mt = 0; mt < 4; ++mt)
            a[mt] = *(const short8*)(X1 + (size_t)(row0 + mt * 16 + l16) * D + kk + quad * 8);
#pragma unroll
        for (int nt = 0; nt < 4; ++nt)
            b[nt] = *(const short8*)(W1b + (size_t)(colw + nt * 16 + l16) * D + kk + quad * 8);
#pragma unroll
        for (int mt = 0; mt < 4; ++mt)
#pragma unroll
            for (int nt = 0; nt < 4; ++nt)
                acc1[mt][nt] = __builtin_amdgcn_mfma_f32_16x16x32_bf16(a[mt], b[nt], acc1[mt][nt], 0, 0, 0);
    }
    for (int kk = 0; kk < D; kk += 32) {
        short8 a[4], b[4];
#pragma unroll
        for (int mt = 0; mt < 4; ++mt)
            a[mt] = *(const short8*)(X2 + (size_t)(row0 + mt * 16 + l16) * D + kk + quad * 8);
#pragma unroll
        for (int nt = 0; nt < 4; ++nt)
            b[nt] = *(const short8*)(W2b + (size_t)(colw + nt * 16 + l16) * D + kk + quad * 8);
#pragma unroll
        for (int mt = 0; mt < 4; ++mt)
#pragma unroll
            for (int nt = 0; nt < 4; ++nt)
                acc2[mt][nt] = __builtin_amdgcn_mfma_f32_16x16x32_bf16(a[mt], b[nt], acc2[mt][nt], 0, 0, 0);
    }

#pragma unroll
    for (int nt = 0; nt < 4; ++nt) {
        int col = colw + nt * 16 + l16;
        float bb1 = b1[col], bb2 = b2[col];
#pragma unroll
        for (int mt = 0; mt < 4; ++mt) {
            int row = row0 + mt * 16 + quad * 4;
#pragma unroll
            for (int r = 0; r < 4; ++r) {
                if (row + r < n) {
                    float v1 = acc1[mt][nt][r] + bb1;
                    v1 = v1 > 0.f ? v1 : 0.01f * v1;
                    float v2 = acc2[mt][nt][r] + bb2;
                    v2 = v2 > 0.f ? v2 : 0.01f * v2;
                    out[(size_t)(row + r) * D + col] = v1 + v2;
                }
            }
        }
    }
}

extern "C" void kernel_launch(void* const* d_in, const int* in_sizes, int n_in,
                              void* d_out, int out_size, void* d_ws, size_t ws_size,
                              hipStream_t stream) {
    const float* ego   = (const float*)d_in[0];
    const float* evals = (const float*)d_in[1];
    const float* W1    = (const float*)d_in[2];
    const float* b1    = (const float*)d_in[3];
    const float* W2    = (const float*)d_in[4];
    const float* b2    = (const float*)d_in[5];
    const int* erows   = (const int*)d_in[6];
    const int* ecols   = (const int*)d_in[7];
    float* out = (float*)d_out;

    int n = in_sizes[0] / D;          // 100000
    int E = in_sizes[1];              // 3200000
    int npad = (n + 63) & ~63;        // 100032
    int NCH = (n + (1 << CHSH) - 1) >> CHSH;   // 13
    int nb = n * NCH;                 // 1.3M buckets
    int np = (nb + 1023) / 1024;      // partial count (<=2048)
    int BW = (nb + 7) / 8;            // bucket-window width (8 windows)
    size_t csr_cap = (size_t)E + 4u * (size_t)nb;   // worst-case padded edges (min-4 pad)

    char* p = (char*)d_ws;
    auto alloc = [&](size_t bytes) {
        char* q = p;
        p += (bytes + 511) & ~(size_t)511;
        return q;
    };
    ushort* ego_bf = (ushort*)alloc((size_t)n * D * 2);      // 51.2 MB
    ushort* X1     = (ushort*)alloc((size_t)npad * D * 2);   // 51.2 MB
    ushort* X2     = (ushort*)alloc((size_t)npad * D * 2);   // 51.2 MB
    ushort* W1b    = (ushort*)alloc((size_t)D * D * 2);
    ushort* W2b    = (ushort*)alloc((size_t)D * D * 2);
    int* bp        = (int*)alloc((size_t)nb * 4);            // 5.2 MB (bumped)
    int* bp2       = (int*)alloc((size_t)(nb + 64) * 4);     // 5.2 MB (pristine + sentinel)
    int* part      = (int*)alloc((size_t)np * 4);
    uint32_t* csr  = (uint32_t*)alloc(csr_cap * 4);          // 33.6 MB (padded)

    // aux edge records (25.6 MB) aliased onto X1: dead until k_spmm writes X1,
    // and k_scatter (the last reader) completes before k_spmm in stream order.
    uint64_t* aux = (uint64_t*)X1;

    hipMemsetAsync(bp, 0, (size_t)nb * 4, stream);
    hipMemsetAsync(csr, 0, csr_cap * 4, stream);   // pad slots must be payload 0
    int EB = (E + 255) / 256;
    k_hist<<<EB, 256, 0, stream>>>(erows, ecols, evals, bp, aux, E, n);
    k_red<<<np, 256, 0, stream>>>(bp, part, nb);
    k_scanpart<<<1, 1024, 0, stream>>>(part, np);
    k_scan3<<<np, 256, 0, stream>>>(bp, bp2, part, nb);
    k_scatter<<<8 * EB, 256, 0, stream>>>(aux, bp, csr, E, BW);

    int n4 = n * (D / 4);
    k_cvt<<<(n4 + 32768 + 255) / 256, 256, 0, stream>>>((const float4*)ego, (ushort4*)ego_bf,
                                                        (const float4*)W1, (const float4*)W2,
                                                        (ushort4*)W1b, (ushort4*)W2b, n4);

    // grid ~single co-resident generation: waves = grid*4, nodes = waves*NPW >= n
    int nwaves = (n + NPW - 1) / NPW;          // 4000
    int nblocks = (nwaves + 3) / 4;            // 1000
    k_spmm<<<nblocks, 256, 0, stream>>>(ego_bf, bp2, csr, X1, X2, n, NCH, nb);

    k_gemm<<<npad / 64, 256, 0, stream>>>(X1, X2, W1b, W2b, b1, b2, out, n);
}

// Round 6
// 831.503 us; speedup vs baseline: 2.1827x; 2.1827x over previous
//
#include <hip/hip_runtime.h>
#include <hip/hip_fp16.h>
#include <stdint.h>

#define D 256
#define CHSH 13   // column-chunk shift: 8192 nodes/chunk = 4.2 MB bf16 rows ~ per-XCD L2

typedef __attribute__((ext_vector_type(8))) short short8;
typedef __attribute__((ext_vector_type(4))) float floatx4;

__device__ __forceinline__ ushort f2bf(float f) {
    union { float f; uint32_t u; } v; v.f = f;
    uint32_t u = v.u;
    u += 0x7fffu + ((u >> 16) & 1u);   // RNE
    return (ushort)(u >> 16);
}
__device__ __forceinline__ float bf2f(ushort h) {
    union { uint32_t u; float f; } v; v.u = ((uint32_t)h) << 16;
    return v.f;
}

// ---------------- bucketed CSR build ----------------
// bucket id = row*NCH + (col>>CHSH); buckets of a row are contiguous, so the
// row's edge range is [bp_excl[row*NCH], bp_excl[(row+1)*NCH]) and edges come
// out ordered by column chunk -> L2-resident gather window in spmm.

// hist + aux-record build: aux[e] = bucket<<32 | (col<<15 | half(val))
// aux is aliased onto X1 (dead until spmm).
__global__ void k_hist(const int* __restrict__ er, const int* __restrict__ ec,
                       const float* __restrict__ ev,
                       int* __restrict__ bp, uint64_t* __restrict__ aux,
                       int E, int NCH) {
    int e = blockIdx.x * 256 + threadIdx.x;
    if (e >= E) return;
    int row = er[e];
    int col = ec[e];
    int b = row * NCH + (col >> CHSH);
    atomicAdd(&bp[b], 1);
    ushort hb = __half_as_ushort(__float2half_rn(ev[e]));   // val in [0,1/32): sign bit free
    uint32_t payload = ((uint32_t)col << 15) | (uint32_t)hb;
    aux[e] = ((uint64_t)(uint32_t)b << 32) | payload;
}

// block b sums bp[b*1024 .. b*1024+1023] -> part[b]
__global__ void k_red(const int* __restrict__ bp, int* __restrict__ part, int nb) {
    __shared__ int s[256];
    int t = threadIdx.x;
    int base = blockIdx.x * 1024 + t * 4;
    int v = 0;
#pragma unroll
    for (int j = 0; j < 4; ++j) if (base + j < nb) v += bp[base + j];
    s[t] = v; __syncthreads();
    for (int off = 128; off; off >>= 1) {
        if (t < off) s[t] += s[t + off];
        __syncthreads();
    }
    if (t == 0) part[blockIdx.x] = s[0];
}

// exclusive scan of part[0..np), np <= 2048, one block of 1024
__global__ __launch_bounds__(1024) void k_scanpart(int* __restrict__ part, int np) {
    __shared__ int s[1024];
    int t = threadIdx.x;
    int p0 = (2 * t < np) ? part[2 * t] : 0;
    int p1 = (2 * t + 1 < np) ? part[2 * t + 1] : 0;
    int v = p0 + p1;
    s[t] = v; __syncthreads();
    for (int off = 1; off < 1024; off <<= 1) {
        int x = (t >= off) ? s[t - off] : 0;
        __syncthreads();
        s[t] += x;
        __syncthreads();
    }
    int excl = s[t] - v;
    if (2 * t < np) part[2 * t] = excl;
    if (2 * t + 1 < np) part[2 * t + 1] = excl + p0;
}

// in-place exclusive scan of bp within each 1024 chunk, + part[b]
__global__ void k_scan3(int* __restrict__ bp, const int* __restrict__ part, int nb) {
    __shared__ int s[256];
    int t = threadIdx.x;
    int base = blockIdx.x * 1024 + t * 4;
    int d0 = 0, d1 = 0, d2 = 0, d3 = 0;
    if (base     < nb) d0 = bp[base];
    if (base + 1 < nb) d1 = bp[base + 1];
    if (base + 2 < nb) d2 = bp[base + 2];
    if (base + 3 < nb) d3 = bp[base + 3];
    int sum = d0 + d1 + d2 + d3;
    s[t] = sum; __syncthreads();
    for (int off = 1; off < 256; off <<= 1) {
        int x = (t >= off) ? s[t - off] : 0;
        __syncthreads();
        s[t] += x;
        __syncthreads();
    }
    int run = part[blockIdx.x] + s[t] - sum;   // exclusive prefix
    if (base     < nb) bp[base]     = run; run += d0;
    if (base + 1 < nb) bp[base + 1] = run; run += d1;
    if (base + 2 < nb) bp[base + 2] = run; run += d2;
    if (base + 3 < nb) bp[base + 3] = run;
}

// windowed, XCD-pinned scatter. 8 windows, window w = buckets [w*BW,(w+1)*BW),
// processed only by blocks with blockIdx&7 == w (round-robin XCD dispatch
// heuristic). Each window's csr slice (~1.6 MB) and bp slice (~650 KB) stay
// resident in one XCD's L2, so scattered 4B writes merge into full lines
// before writeback. aux re-scans are absorbed by the 256 MB L3.
// Afterwards bp[i] = end of bucket i.
__global__ void k_scatter(const uint64_t* __restrict__ aux,
                          int* __restrict__ bp, uint32_t* __restrict__ csr,
                          int E, int BW) {
    int xcd = blockIdx.x & 7;            // = window id
    int j = blockIdx.x >> 3;
    int e = j * 256 + threadIdx.x;
    if (e >= E) return;
    uint64_t a = aux[e];
    int b = (int)(a >> 32);
    int lo = xcd * BW;
    if (b < lo || b >= lo + BW) return;  // not this window's edge
    int p = atomicAdd(&bp[b], 1);
    csr[p] = (uint32_t)a;
}

// ---------------- conversions (ego + W fused) ----------------
__global__ void k_cvt(const float4* __restrict__ ego, ushort4* __restrict__ ego_bf,
                      const float4* __restrict__ W1, const float4* __restrict__ W2,
                      ushort4* __restrict__ W1b, ushort4* __restrict__ W2b, int n4) {
    int i = blockIdx.x * 256 + threadIdx.x;
    const float4* src;
    ushort4* dst;
    if (i < n4) { src = ego + i; dst = ego_bf + i; }
    else {
        int j = i - n4;
        if (j >= 32768) return;
        int k = j & 16383;
        src = ((j < 16384) ? W1 : W2) + k;
        dst = ((j < 16384) ? W1b : W2b) + k;
    }
    float4 f = *src;
    ushort4 u;
    u.x = f2bf(f.x); u.y = f2bf(f.y); u.z = f2bf(f.z); u.w = f2bf(f.w);
    *dst = u;
}

// ---------------- SpMM + bi-interaction inputs ----------------
// one wave per node; lane owns 4 consecutive features; edge loop unrolled x16
// (16 gathers in flight), plus ONE masked 16-wide tail group (payload 0 ->
// gathers row 0, adds 0.0) so no edge is ever processed at MLP 1.
__global__ void k_spmm(const ushort* __restrict__ ego_bf, const int* __restrict__ bp,
                       const uint32_t* __restrict__ csr,
                       ushort* __restrict__ X1, ushort* __restrict__ X2, int n, int NCH) {
    int gtid = blockIdx.x * 256 + threadIdx.x;
    int node = gtid >> 6;
    int lane = gtid & 63;
    if (node >= n) return;
    // post-scatter bp[i] = end of bucket i, so row range is:
    int beg = (node == 0) ? 0 : bp[node * NCH - 1];
    int end = bp[(node + 1) * NCH - 1];
    int d0 = lane * 4;
    float a0 = 0.f, a1 = 0.f, a2 = 0.f, a3 = 0.f;
    int e = beg;
    for (; e + 16 <= end; e += 16) {
        uint32_t w[16];
#pragma unroll
        for (int j = 0; j < 16; ++j) w[j] = csr[e + j];
        ushort4 u[16];
#pragma unroll
        for (int j = 0; j < 16; ++j)
            u[j] = *(const ushort4*)(ego_bf + (size_t)(w[j] >> 15) * D + d0);
#pragma unroll
        for (int j = 0; j < 16; ++j) {
            float v = __half2float(__ushort_as_half((ushort)(w[j] & 0x7fff)));
            a0 += v * bf2f(u[j].x);
            a1 += v * bf2f(u[j].y);
            a2 += v * bf2f(u[j].z);
            a3 += v * bf2f(u[j].w);
        }
    }
    if (e < end) {
        // masked 16-wide tail: guards are wave-uniform; w=0 => row 0 * 0.0
        uint32_t w[16];
#pragma unroll
        for (int j = 0; j < 16; ++j) w[j] = (e + j < end) ? csr[e + j] : 0u;
        ushort4 u[16];
#pragma unroll
        for (int j = 0; j < 16; ++j)
            u[j] = *(const ushort4*)(ego_bf + (size_t)(w[j] >> 15) * D + d0);
#pragma unroll
        for (int j = 0; j < 16; ++j) {
            float v = __half2float(__ushort_as_half((ushort)(w[j] & 0x7fff)));
            a0 += v * bf2f(u[j].x);
            a1 += v * bf2f(u[j].y);
            a2 += v * bf2f(u[j].z);
            a3 += v * bf2f(u[j].w);
        }
    }
    ushort4 eg = *(const ushort4*)(ego_bf + (size_t)node * D + d0);
    float e0 = bf2f(eg.x), e1 = bf2f(eg.y), e2 = bf2f(eg.z), e3 = bf2f(eg.w);
    ushort4 o1, o2;
    o1.x = f2bf(e0 + a0); o2.x = f2bf(e0 * a0);
    o1.y = f2bf(e1 + a1); o2.y = f2bf(e1 * a1);
    o1.z = f2bf(e2 + a2); o2.z = f2bf(e2 * a2);
    o1.w = f2bf(e3 + a3); o2.w = f2bf(e3 * a3);
    *(ushort4*)(X1 + (size_t)node * D + d0) = o1;
    *(ushort4*)(X2 + (size_t)node * D + d0) = o2;
}

// ---------------- fused dual GEMM + epilogue ----------------
__global__ __launch_bounds__(256) void k_gemm(
        const ushort* __restrict__ X1, const ushort* __restrict__ X2,
        const ushort* __restrict__ W1b, const ushort* __restrict__ W2b,
        const float* __restrict__ b1, const float* __restrict__ b2,
        float* __restrict__ out, int n) {
    int lane = threadIdx.x & 63;
    int w = threadIdx.x >> 6;
    int l16 = lane & 15, quad = lane >> 4;
    int row0 = blockIdx.x * 64;
    int colw = w * 64;

    floatx4 acc1[4][4], acc2[4][4];
#pragma unroll
    for (int i = 0; i < 4; ++i)
#pragma unroll
        for (int j = 0; j < 4; ++j) { acc1[i][j] = (floatx4)0.f; acc2[i][j] = (floatx4)0.f; }

    for (int kk = 0; kk < D; kk += 32) {
        short8 a[4], b[4];
#pragma unroll
        for (int mt = 0; mt < 4; ++mt)
            a[mt] = *(const short8*)(X1 + (size_t)(row0 + mt * 16 + l16) * D + kk + quad * 8);
#pragma unroll
        for (int nt = 0; nt < 4; ++nt)
            b[nt] = *(const short8*)(W1b + (size_t)(colw + nt * 16 + l16) * D + kk + quad * 8);
#pragma unroll
        for (int mt = 0; mt < 4; ++mt)
#pragma unroll
            for (int nt = 0; nt < 4; ++nt)
                acc1[mt][nt] = __builtin_amdgcn_mfma_f32_16x16x32_bf16(a[mt], b[nt], acc1[mt][nt], 0, 0, 0);
    }
    for (int kk = 0; kk < D; kk += 32) {
        short8 a[4], b[4];
#pragma unroll
        for (int mt = 0; mt < 4; ++mt)
            a[mt] = *(const short8*)(X2 + (size_t)(row0 + mt * 16 + l16) * D + kk + quad * 8);
#pragma unroll
        for (int nt = 0; nt < 4; ++nt)
            b[nt] = *(const short8*)(W2b + (size_t)(colw + nt * 16 + l16) * D + kk + quad * 8);
#pragma unroll
        for (int mt = 0; mt < 4; ++mt)
#pragma unroll
            for (int nt = 0; nt < 4; ++nt)
                acc2[mt][nt] = __builtin_amdgcn_mfma_f32_16x16x32_bf16(a[mt], b[nt], acc2[mt][nt], 0, 0, 0);
    }

#pragma unroll
    for (int nt = 0; nt < 4; ++nt) {
        int col = colw + nt * 16 + l16;
        float bb1 = b1[col], bb2 = b2[col];
#pragma unroll
        for (int mt = 0; mt < 4; ++mt) {
            int row = row0 + mt * 16 + quad * 4;
#pragma unroll
            for (int r = 0; r < 4; ++r) {
                if (row + r < n) {
                    float v1 = acc1[mt][nt][r] + bb1;
                    v1 = v1 > 0.f ? v1 : 0.01f * v1;
                    float v2 = acc2[mt][nt][r] + bb2;
                    v2 = v2 > 0.f ? v2 : 0.01f * v2;
                    out[(size_t)(row + r) * D + col] = v1 + v2;
                }
            }
        }
    }
}

extern "C" void kernel_launch(void* const* d_in, const int* in_sizes, int n_in,
                              void* d_out, int out_size, void* d_ws, size_t ws_size,
                              hipStream_t stream) {
    const float* ego   = (const float*)d_in[0];
    const float* evals = (const float*)d_in[1];
    const float* W1    = (const float*)d_in[2];
    const float* b1    = (const float*)d_in[3];
    const float* W2    = (const float*)d_in[4];
    const float* b2    = (const float*)d_in[5];
    const int* erows   = (const int*)d_in[6];
    const int* ecols   = (const int*)d_in[7];
    float* out = (float*)d_out;

    int n = in_sizes[0] / D;          // 100000
    int E = in_sizes[1];              // 3200000
    int npad = (n + 63) & ~63;        // 100032
    int NCH = (n + (1 << CHSH) - 1) >> CHSH;   // 13
    int nb = n * NCH;                 // 1.3M buckets
    int np = (nb + 1023) / 1024;      // partial count (<=2048)
    int BW = (nb + 7) / 8;            // bucket-window width (8 windows)

    char* p = (char*)d_ws;
    auto alloc = [&](size_t bytes) {
        char* q = p;
        p += (bytes + 511) & ~(size_t)511;
        return q;
    };
    ushort* ego_bf = (ushort*)alloc((size_t)n * D * 2);      // 51.2 MB
    ushort* X1     = (ushort*)alloc((size_t)npad * D * 2);   // 51.2 MB
    ushort* X2     = (ushort*)alloc((size_t)npad * D * 2);   // 51.2 MB
    ushort* W1b    = (ushort*)alloc((size_t)D * D * 2);
    ushort* W2b    = (ushort*)alloc((size_t)D * D * 2);
    int* bp        = (int*)alloc((size_t)nb * 4);            // 5.2 MB
    int* part      = (int*)alloc((size_t)np * 4);
    uint32_t* csr  = (uint32_t*)alloc((size_t)E * 4);        // 12.8 MB

    // aux edge records (25.6 MB) aliased onto X1: dead until k_spmm writes X1,
    // and k_scatter (the last reader) completes before k_spmm in stream order.
    uint64_t* aux = (uint64_t*)X1;

    hipMemsetAsync(bp, 0, (size_t)nb * 4, stream);
    int EB = (E + 255) / 256;
    k_hist<<<EB, 256, 0, stream>>>(erows, ecols, evals, bp, aux, E, NCH);
    k_red<<<np, 256, 0, stream>>>(bp, part, nb);
    k_scanpart<<<1, 1024, 0, stream>>>(part, np);
    k_scan3<<<np, 256, 0, stream>>>(bp, part, nb);
    k_scatter<<<8 * EB, 256, 0, stream>>>(aux, bp, csr, E, BW);

    int n4 = n * (D / 4);
    k_cvt<<<(n4 + 32768 + 255) / 256, 256, 0, stream>>>((const float4*)ego, (ushort4*)ego_bf,
                                                        (const float4*)W1, (const float4*)W2,
                                                        (ushort4*)W1b, (ushort4*)W2b, n4);

    k_spmm<<<(n * 64 + 255) / 256, 256, 0, stream>>>(ego_bf, bp, csr, X1, X2, n, NCH);

    k_gemm<<<npad / 64, 256, 0, stream>>>(X1, X2, W1b, W2b, b1, b2, out, n);
}